// Round 6
// baseline (42790.308 us; speedup 1.0000x reference)
//
#include <hip/hip_runtime.h>
#include <hip/hip_bf16.h>

// Problem constants
#define HH 1024
#define BB 128
#define TT 512
#define NWG 128      // persistent workgroups: (MP=4) x (NP=32)
#define NTH 512      // 8 waves: 4 output tiles (2M x 2N) x 2 K-halves
#define NP 32

typedef float        f32x4 __attribute__((ext_vector_type(4)));
typedef short        s16x8 __attribute__((ext_vector_type(8)));
typedef unsigned int u32x2 __attribute__((ext_vector_type(2)));

__device__ __forceinline__ unsigned short bf16b(float f) {
    union { __hip_bfloat16 h; unsigned short u; } cv;
    cv.h = __float2bfloat16(f);
    return cv.u;
}

__device__ __forceinline__ float gelu_exact(float x) {
    return 0.5f * x * (1.0f + erff(x * 0.70710678118654752440f));
}

// --- device-coherent (L1+L2-bypass) accesses: producer/consumer data across
// WGs within one kernel. Keeps L2 clean for weights.
__device__ __forceinline__ void sc_load_b16x8(s16x8& v, const unsigned short* p) {
    asm volatile("global_load_dwordx4 %0, %1, off sc0 sc1" : "=v"(v) : "v"(p));
}
__device__ __forceinline__ void sc_load_u32x2(u32x2& v, const unsigned* p) {
    asm volatile("global_load_dwordx2 %0, %1, off sc0 sc1" : "=v"(v) : "v"(p));
}
__device__ __forceinline__ void sc_store_b16(unsigned short* p, unsigned int v) {
    asm volatile("global_store_short %0, %1, off sc0 sc1" :: "v"(p), "v"(v) : "memory");
}
__device__ __forceinline__ void sc_store_u32(unsigned* p, unsigned int v) {
    asm volatile("global_store_dword %0, %1, off sc0 sc1" :: "v"(p), "v"(v) : "memory");
}
// --- plain cached load in the hand-counted asm stream (weights -> L2 hit).
__device__ __forceinline__ void pl_load_b16x8(s16x8& v, const unsigned short* p) {
    asm volatile("global_load_dwordx4 %0, %1, off" : "=v"(v) : "v"(p));
}
// --- non-temporal store for streaming Out writes (no L2 pollution).
__device__ __forceinline__ void nt_store_f32(float* p, float v) {
    asm volatile("global_store_dword %0, %1, off nt" :: "v"(p), "v"(v) : "memory");
}
__device__ __forceinline__ void vm_wait0() {
    asm volatile("s_waitcnt vmcnt(0)" ::: "memory");
    __builtin_amdgcn_sched_barrier(0);   // rule #18
}

// ---------------------------------------------------------------------------
// Pack fp32 weight W[K][N] (row-major) into MFMA B-fragment layout, bf16:
//   P[((ntile*KT + ktile)*64 + lane)*8 + j] =
//       bf16(W[ktile*32 + (lane>>4)*8 + j][ntile*16 + (lane&15)])
// ---------------------------------------------------------------------------
__global__ __launch_bounds__(256) void pack_w_kernel(const float* __restrict__ W,
                                                     unsigned short* __restrict__ P,
                                                     int K, int N) {
    int tid = blockIdx.x * 256 + threadIdx.x;
    int KT = K >> 5;
    int total = (N >> 4) * KT * 64;
    if (tid >= total) return;
    int lane  = tid & 63;
    int ktile = (tid >> 6) % KT;
    int ntile = (tid >> 6) / KT;
    int k0 = ktile * 32 + (lane >> 4) * 8;
    int n  = ntile * 16 + (lane & 15);
    unsigned short tmp[8];
#pragma unroll
    for (int j = 0; j < 8; ++j)
        tmp[j] = bf16b(W[(size_t)(k0 + j) * N + n]);
    *reinterpret_cast<s16x8*>(P + (size_t)tid * 8) = *reinterpret_cast<const s16x8*>(tmp);
}

// ---------------------------------------------------------------------------
// Flag-array device barrier. Arrive: drain stores, one sc-store per WG.
// Wait: EVERY wave polls all NWG slots independently (2 per lane) -> no
// trailing __syncthreads serialization.
// ---------------------------------------------------------------------------
__device__ __forceinline__ void gbar_arrive(unsigned* slots, unsigned rnd) {
    asm volatile("s_waitcnt vmcnt(0)" ::: "memory");  // drain my sc/nt stores
    __syncthreads();                                   // all 8 waves drained
    if (threadIdx.x == 0)
        sc_store_u32(slots + blockIdx.x, rnd);
}
__device__ __forceinline__ void gbar_wait(const unsigned* slots, unsigned rnd) {
    const unsigned* p = slots + ((threadIdx.x & 63) << 1);
    bool done;
    do {
        u32x2 v;
        sc_load_u32x2(v, p);
        asm volatile("s_waitcnt vmcnt(0)" ::: "memory");
        done = __all(v.x >= rnd && v.y >= rnd);
    } while (!done);
    __builtin_amdgcn_sched_barrier(0);
}

// ---------------------------------------------------------------------------
// 2-deep software-pipelined K-loop: A via sc loads (activations, coherent),
// B via plain loads (weights, L2-resident). 8 kt per batch = 16 loads.
// Counted vmcnt(16) keeps the next batch in flight across each MFMA cluster;
// only the last batch drains to 0.  sched_barrier(0) after each wait pins
// the MFMAs below it (rule #18).
// ---------------------------------------------------------------------------
template <int NBLK>
__device__ __forceinline__ f32x4 kloop_pipe(const unsigned short* Abase,
                                            const unsigned short* bp) {
    f32x4 acc = {};
    s16x8 a[2][8], b[2][8];
#pragma unroll
    for (int j = 0; j < 8; ++j)
        sc_load_b16x8(a[0][j], Abase + (size_t)j * 32);
#pragma unroll
    for (int j = 0; j < 8; ++j)
        pl_load_b16x8(b[0][j], bp + (size_t)j * 512);
#pragma unroll
    for (int blk = 0; blk < NBLK; ++blk) {
        const int cur = blk & 1, nxt = cur ^ 1;
        if (blk + 1 < NBLK) {
#pragma unroll
            for (int j = 0; j < 8; ++j)
                sc_load_b16x8(a[nxt][j], Abase + (size_t)((blk + 1) * 8 + j) * 32);
#pragma unroll
            for (int j = 0; j < 8; ++j)
                pl_load_b16x8(b[nxt][j], bp + (size_t)((blk + 1) * 8 + j) * 512);
            asm volatile("s_waitcnt vmcnt(16)" ::: "memory");
        } else {
            asm volatile("s_waitcnt vmcnt(0)" ::: "memory");
        }
        __builtin_amdgcn_sched_barrier(0);
#pragma unroll
        for (int j = 0; j < 8; ++j)
            acc = __builtin_amdgcn_mfma_f32_16x16x32_bf16(a[cur][j], b[cur][j], acc, 0, 0, 0);
    }
    return acc;
}

// K-loop over the fp32 input frame: all plain cached loads (L1/L2), pure C++
// so the compiler software-pipelines it itself.
__device__ __forceinline__ f32x4 kloop_x(const float* xt, const unsigned short* bp) {
    f32x4 acc = {};
#pragma unroll 4
    for (int kt = 0; kt < 32; ++kt) {
        f32x4 lo = *reinterpret_cast<const f32x4*>(xt + kt * 32);
        f32x4 hi = *reinterpret_cast<const f32x4*>(xt + kt * 32 + 4);
        s16x8 a;
#pragma unroll
        for (int j = 0; j < 4; ++j) {
            a[j]     = (short)bf16b(lo[j]);
            a[j + 4] = (short)bf16b(hi[j]);
        }
        s16x8 b = *reinterpret_cast<const s16x8*>(bp + (size_t)kt * 512);
        acc = __builtin_amdgcn_mfma_f32_16x16x32_bf16(a, b, acc, 0, 0, 0);
    }
    return acc;
}

// ---------------------------------------------------------------------------
// Persistent kernel. Partition per GEMM (M=128, N=1024):
//   ng = wg & 31 -> 32-col slice; mg = wg >> 5 -> 32-row slice.
//   (wg % 8 == ng % 8 keeps all M-copies of a weight slice on one XCD.)
// 8 waves: tile = w&3 (2M x 2N of 16x16), khalf = w>>2 splits K.
// khalf-1 partials reduced into khalf-0 via 4 KB LDS.
// Weights/biases/X: plain cached. Activations: sc0sc1. Out: nt.
// ---------------------------------------------------------------------------
__global__ __launch_bounds__(512, 1) void persist_kernel(
    const float* __restrict__ X,
    const unsigned short* __restrict__ p_a1, const float* __restrict__ ab1,
    const unsigned short* __restrict__ p_a2, const float* __restrict__ ab2,
    const unsigned short* __restrict__ p_g1, const float* __restrict__ gb1,
    const unsigned short* __restrict__ p_g2, const float* __restrict__ gb2,
    float* __restrict__ Out,
    unsigned short* state, unsigned short* h1, unsigned short* albf,
    unsigned short* h2,
    unsigned* slots)
{
    __shared__ f32x4 red[4][64];         // 4 KB: split-K reduction

    const int wg    = blockIdx.x;
    const int ng    = wg & (NP - 1);
    const int mg    = wg >> 5;
    const int tid   = threadIdx.x;
    const int lane  = tid & 63;
    const int w     = tid >> 6;       // 0..7
    const int tile  = w & 3;          // 2M x 2N
    const int khalf = w >> 2;         // 0..1
    const int wm    = tile >> 1;
    const int wn    = tile & 1;
    const int r     = lane & 15;
    const int q     = lane >> 4;

    const int mrow  = mg * 32 + wm * 16;
    const int ncol  = ng * 32 + wn * 16;
    const int ntile = ncol >> 4;

    const size_t arow_off = (size_t)(mrow + r) * HH + q * 8;
    const float* xrow = X + (size_t)(mrow + r) * (TT * HH) + q * 8;

    const unsigned short* bpa1 = p_a1 + ((size_t)ntile * 64) * 512 + (size_t)lane * 8;
    const unsigned short* bpg1 = p_g1 + ((size_t)ntile * 64) * 512 + (size_t)lane * 8;
    const unsigned short* bpa2 = p_a2 + ((size_t)ntile * 32) * 512 + (size_t)lane * 8;
    const unsigned short* bpg2 = p_g2 + ((size_t)ntile * 32) * 512 + (size_t)lane * 8;

    const float biasA1 = ab1[ncol + r];
    const float biasA2 = ab2[ncol + r];
    const float biasG1 = gb1[ncol + r];
    const float biasG2 = gb2[ncol + r];

    float al_reg[4] = {0.f, 0.f, 0.f, 0.f};   // fp32 'aligned' tile (khalf 0)
    unsigned rnd = 0;

    for (int t = 0; t < TT; ++t) {
        const float* xt = xrow + (size_t)t * HH;

        // ------- G1: h1 = gelu(concat(x_t, state) @ aw1 + ab1), K=2048 -----
        {
            f32x4 acc;
            if (khalf == 0) acc = kloop_x(xt, bpa1);                 // K 0..1023
            else            acc = kloop_pipe<4>(state + arow_off,    // K 1024..2047
                                                bpa1 + (size_t)32 * 512);
            if (khalf == 1) red[tile][lane] = acc;
            __syncthreads();
            if (khalf == 0) {
                acc += red[tile][lane];
#pragma unroll
                for (int j = 0; j < 4; ++j) {
                    float v = acc[j] + biasA1;
                    sc_store_b16(h1 + (size_t)(mrow + q * 4 + j) * HH + ncol + r,
                                 bf16b(gelu_exact(v)));
                }
            }
        }
        ++rnd; gbar_arrive(slots, rnd); gbar_wait(slots, rnd);

        // ------- G2: aligned = h1 @ aw2 + ab2, K=1024 ----------------------
        {
            f32x4 acc = kloop_pipe<2>(h1 + arow_off + (size_t)khalf * 512,
                                      bpa2 + (size_t)khalf * 16 * 512);
            if (khalf == 1) red[tile][lane] = acc;
            __syncthreads();
            if (khalf == 0) {
                acc += red[tile][lane];
#pragma unroll
                for (int j = 0; j < 4; ++j) {
                    float v = acc[j] + biasA2;
                    al_reg[j] = v;
                    sc_store_b16(albf + (size_t)(mrow + q * 4 + j) * HH + ncol + r,
                                 bf16b(v));
                }
            }
        }
        ++rnd; gbar_arrive(slots, rnd); gbar_wait(slots, rnd);

        // ------- G3: h2 = gelu(concat(x_t, aligned) @ gw1 + gb1), K=2048 ---
        {
            f32x4 acc;
            if (khalf == 0) acc = kloop_x(xt, bpg1);
            else            acc = kloop_pipe<4>(albf + arow_off,
                                                bpg1 + (size_t)32 * 512);
            if (khalf == 1) red[tile][lane] = acc;
            __syncthreads();
            if (khalf == 0) {
                acc += red[tile][lane];
#pragma unroll
                for (int j = 0; j < 4; ++j) {
                    float v = acc[j] + biasG1;
                    sc_store_b16(h2 + (size_t)(mrow + q * 4 + j) * HH + ncol + r,
                                 bf16b(gelu_exact(v)));
                }
            }
        }
        ++rnd; gbar_arrive(slots, rnd); gbar_wait(slots, rnd);

        // ------- G4: gate = sigmoid(h2 @ gw2 + gb2); blend; next state -----
        {
            f32x4 acc = kloop_pipe<2>(h2 + arow_off + (size_t)khalf * 512,
                                      bpg2 + (size_t)khalf * 16 * 512);
            if (khalf == 1) red[tile][lane] = acc;
            __syncthreads();
            if (khalf == 0) {
                acc += red[tile][lane];
#pragma unroll
                for (int j = 0; j < 4; ++j) {
                    int row = mrow + q * 4 + j;
                    int col = ncol + r;
                    float gl = acc[j] + biasG2;
                    float g  = 1.0f / (1.0f + expf(-gl));
                    float xv = X[(size_t)row * (TT * HH) + (size_t)t * HH + col];
                    float o  = g * al_reg[j] + (1.0f - g) * xv;
                    nt_store_f32(Out + (size_t)row * (TT * HH) + (size_t)t * HH + col, o);
                    sc_store_b16(state + (size_t)row * HH + col, bf16b(o));
                }
            }
        }
        ++rnd; gbar_arrive(slots, rnd); gbar_wait(slots, rnd);
    }
}

extern "C" void kernel_launch(void* const* d_in, const int* in_sizes, int n_in,
                              void* d_out, int out_size, void* d_ws, size_t ws_size,
                              hipStream_t stream) {
    (void)in_sizes; (void)n_in; (void)out_size; (void)ws_size;
    const float* X   = (const float*)d_in[0];
    const float* aw1 = (const float*)d_in[1];
    const float* ab1 = (const float*)d_in[2];
    const float* aw2 = (const float*)d_in[3];
    const float* ab2 = (const float*)d_in[4];
    const float* gw1 = (const float*)d_in[5];
    const float* gb1 = (const float*)d_in[6];
    const float* gw2 = (const float*)d_in[7];
    const float* gb2 = (const float*)d_in[8];
    float* Out = (float*)d_out;

    char* ws = (char*)d_ws;
    unsigned short* p_a1 = (unsigned short*)(ws);                 // 4 MB
    unsigned short* p_g1 = (unsigned short*)(ws + (4u  << 20));   // 4 MB
    unsigned short* p_a2 = (unsigned short*)(ws + (8u  << 20));   // 2 MB
    unsigned short* p_g2 = (unsigned short*)(ws + (10u << 20));   // 2 MB
    char* ctrl = ws + (12u << 20);
    unsigned* slots = (unsigned*)ctrl;                            // NWG u32
    unsigned short* state = (unsigned short*)(ctrl + 4096);       // 256 KB
    unsigned short* h1    = state + (size_t)BB * HH;              // 256 KB
    unsigned short* albf  = h1    + (size_t)BB * HH;              // 256 KB
    unsigned short* h2    = albf  + (size_t)BB * HH;              // 256 KB

    pack_w_kernel<<<(64 * 64 * 64 + 255) / 256, 256, 0, stream>>>(aw1, p_a1, 2048, 1024);
    pack_w_kernel<<<(64 * 64 * 64 + 255) / 256, 256, 0, stream>>>(gw1, p_g1, 2048, 1024);
    pack_w_kernel<<<(64 * 32 * 64 + 255) / 256, 256, 0, stream>>>(aw2, p_a2, 1024, 1024);
    pack_w_kernel<<<(64 * 32 * 64 + 255) / 256, 256, 0, stream>>>(gw2, p_g2, 1024, 1024);
    // Zero barrier slots + recurrent state every call (graph-replay safe).
    hipMemsetAsync(ctrl, 0, 4096 + (size_t)BB * HH * sizeof(unsigned short), stream);

    persist_kernel<<<NWG, NTH, 0, stream>>>(X, p_a1, ab1, p_a2, ab2,
                                            p_g1, gb1, p_g2, gb2,
                                            Out, state, h1, albf, h2,
                                            slots);
}